// Round 3
// baseline (859.597 us; speedup 1.0000x reference)
//
#include <hip/hip_runtime.h>
#include <hip/hip_bf16.h>
#include <math.h>

// Problem constants (from reference)
#define S_   512
#define B_   32
#define D_   256
#define H_   8
#define DH_  32
#define E_   (H_*(5*DH_+2))   // 1296
#define SB_  (S_*B_)          // 16384
#define LN_EPSF 1e-5f
#define PFA_ 4                // ff_scan prefetch distance (steps)
#define PFB_ 3                // rec_scan prefetch distance (steps)

// ---------------- reductions ----------------
__device__ __forceinline__ float wave_sum64(float v){
  #pragma unroll
  for (int m = 32; m >= 1; m >>= 1) v += __shfl_xor(v, m, 64);
  return v;
}
__device__ __forceinline__ float gsum32(float v){
  #pragma unroll
  for (int m = 16; m >= 1; m >>= 1) v += __shfl_xor(v, m, 32);
  return v;
}
__device__ __forceinline__ float gmax32(float v){
  #pragma unroll
  for (int m = 16; m >= 1; m >>= 1) v = fmaxf(v, __shfl_xor(v, m, 32));
  return v;
}

// ---------------- LayerNorm: one block per (s,b) row ----------------
__global__ __launch_bounds__(256) void ln_kernel(const float* __restrict__ x,
                                                 const float* __restrict__ g,
                                                 const float* __restrict__ b,
                                                 float* __restrict__ o){
  __shared__ float sbuf[4];
  const int row = blockIdx.x, tid = threadIdx.x;
  const float v = x[(size_t)row*D_ + tid];
  float s = wave_sum64(v);
  if ((tid & 63) == 0) sbuf[tid >> 6] = s;
  __syncthreads();
  const float mu = (sbuf[0]+sbuf[1]+sbuf[2]+sbuf[3]) * (1.f/D_);
  __syncthreads();
  const float d = v - mu;
  float s2 = wave_sum64(d*d);
  if ((tid & 63) == 0) sbuf[tid >> 6] = s2;
  __syncthreads();
  const float var = (sbuf[0]+sbuf[1]+sbuf[2]+sbuf[3]) * (1.f/D_);
  const float rstd = rsqrtf(var + LN_EPSF);
  o[(size_t)row*D_ + tid] = d*rstd*g[tid] + b[tid];
}

// ---------------- GEMM (C[m][n] = sum_k A[m][k]*B[n][k] (+ X)) ----------------
template<bool ADD>
__global__ __launch_bounds__(256) void gemm_bt(const float* __restrict__ A,
                                               const float* __restrict__ Bm,
                                               const float* __restrict__ X,
                                               float* __restrict__ C,
                                               int M, int N, int K){
  const int BM=128, BN=128, BK=16;
  __shared__ float As[BK][BM+4];
  __shared__ float Bs[BK][BN+4];
  const int tid = threadIdx.x;
  const int m0 = blockIdx.y*BM, n0 = blockIdx.x*BN;
  const int tx = tid & 15, ty = tid >> 4;
  float acc[8][8];
  #pragma unroll
  for (int i=0;i<8;i++)
    #pragma unroll
    for (int j=0;j<8;j++) acc[i][j]=0.f;

  const int lrow = tid >> 2;         // 0..63
  const int lcol = (tid & 3) << 2;   // 0,4,8,12

  for (int k0=0;k0<K;k0+=BK){
    #pragma unroll
    for (int p=0;p<2;p++){
      const int row = lrow + p*64;
      const float4 va = *(const float4*)(A + (size_t)(m0+row)*K + k0 + lcol);
      As[lcol+0][row]=va.x; As[lcol+1][row]=va.y; As[lcol+2][row]=va.z; As[lcol+3][row]=va.w;
      const int nrow = n0 + row;
      float4 vb = make_float4(0.f,0.f,0.f,0.f);
      if (nrow < N) vb = *(const float4*)(Bm + (size_t)nrow*K + k0 + lcol);
      Bs[lcol+0][row]=vb.x; Bs[lcol+1][row]=vb.y; Bs[lcol+2][row]=vb.z; Bs[lcol+3][row]=vb.w;
    }
    __syncthreads();
    #pragma unroll
    for (int k=0;k<BK;k++){
      float a[8], bb[8];
      *(float4*)&a[0]  = *(const float4*)&As[k][ty*8];
      *(float4*)&a[4]  = *(const float4*)&As[k][ty*8+4];
      *(float4*)&bb[0] = *(const float4*)&Bs[k][tx*8];
      *(float4*)&bb[4] = *(const float4*)&Bs[k][tx*8+4];
      #pragma unroll
      for (int i=0;i<8;i++)
        #pragma unroll
        for (int j=0;j<8;j++) acc[i][j] = fmaf(a[i], bb[j], acc[i][j]);
    }
    __syncthreads();
  }
  #pragma unroll
  for (int i=0;i<8;i++){
    const size_t m = (size_t)(m0 + ty*8 + i);
    #pragma unroll
    for (int j=0;j<8;j+=4){
      const int n = n0 + tx*8 + j;
      if (n < N){
        float4 r = make_float4(acc[i][j],acc[i][j+1],acc[i][j+2],acc[i][j+3]);
        if (ADD){
          const float4 xv = *(const float4*)(X + m*N + n);
          r.x+=xv.x; r.y+=xv.y; r.z+=xv.z; r.w+=xv.w;
        }
        *(float4*)(C + m*N + n) = r;
      }
    }
  }
}

// ---------------- activations, in-place on qkv [SB][H][162] ----------------
__global__ __launch_bounds__(256) void act_kernel(float* __restrict__ qkv){
  const int sb = blockIdx.x;
  const int head = threadIdx.x >> 5;
  const int i = threadIdx.x & 31;
  float* base = qkv + (size_t)sb*E_ + head*(5*DH_+2);
  float qv  = base[i];
  float kv  = base[DH_ + i];
  float rkv = base[3*DH_ + i];
  qv = qv > 0.f ? qv + 1.f : __expf(qv);
  kv = kv > 0.f ? kv + 1.f : __expf(kv);
  const float qs = gsum32(qv);
  const float ks = gsum32(kv);
  const float rm = gmax32(rkv);
  const float re = __expf(rkv - rm);
  const float rs = gsum32(re);
  base[i]         = qv / qs;
  base[DH_ + i]   = kv / ks;
  base[3*DH_ + i] = re / rs;
  if (i < 2){
    const float bv = base[5*DH_ + i];
    base[5*DH_ + i] = 1.f/(1.f + __expf(-bv));
  }
}

// ---------------- ff scan: z_t = W_t . q_t, delta-rule W ----------------
// One pair (b,h) per 64-lane wave; lane (r,p) owns columns p*16..p*16+15 of
// row r. No h-dependency -> critical path is just the delta chain
// (dot1 -> coef -> update). z is stored IN-PLACE into qkv's dead q-slot.
__global__ __launch_bounds__(64) void ff_scan(float* __restrict__ qkv){
  const int pair = blockIdx.x;
  const int tid  = threadIdx.x;
  const int r    = tid & 31;
  const int p    = tid >> 5;
  const int co   = p*16;              // column offset

  float W[16];
  #pragma unroll
  for (int i=0;i<16;i++) W[i]=0.f;

  float* base = qkv + (size_t)(pair>>3)*E_ + (pair&7)*(5*DH_+2);
  const size_t step = (size_t)B_*E_;

  // prefetch regs (static-indexed)
  float4 fq[PFA_][4], fk[PFA_][4];
  float  fv[PFA_], fb[PFA_];
  #pragma unroll
  for (int u=0;u<PFA_;u++){
    const float* pp = base + (size_t)u*step;
    #pragma unroll
    for (int j=0;j<4;j++){
      fq[u][j] = *(const float4*)(pp + co + 4*j);            // q
      fk[u][j] = *(const float4*)(pp + DH_ + co + 4*j);      // k
    }
    fv[u] = pp[2*DH_ + r];                                   // v[r]
    fb[u] = pp[5*DH_];                                       // beta
  }

  for (int sc=0; sc<S_; sc+=PFA_){
    #pragma unroll
    for (int u=0; u<PFA_; ++u){
      const int s = sc + u;
      float4 q0=fq[u][0],q1=fq[u][1],q2=fq[u][2],q3=fq[u][3];
      float4 k0=fk[u][0],k1=fk[u][1],k2=fk[u][2],k3=fk[u][3];
      const float vv=fv[u], bb=fb[u];
      if (s + PFA_ < S_){
        const float* pp = base + (size_t)(s+PFA_)*step;
        #pragma unroll
        for (int j=0;j<4;j++){
          fq[u][j] = *(const float4*)(pp + co + 4*j);
          fk[u][j] = *(const float4*)(pp + DH_ + co + 4*j);
        }
        fv[u] = pp[2*DH_ + r];
        fb[u] = pp[5*DH_];
      }

      // v_old partial = W[r,cols] . k[cols]
      float a0,a1,a2,a3;
      a0 = W[0]*k0.x;            a1 = W[1]*k0.y;
      a2 = W[2]*k0.z;            a3 = W[3]*k0.w;
      a0 = fmaf(W[4], k1.x,a0);  a1 = fmaf(W[5], k1.y,a1);
      a2 = fmaf(W[6], k1.z,a2);  a3 = fmaf(W[7], k1.w,a3);
      a0 = fmaf(W[8], k2.x,a0);  a1 = fmaf(W[9], k2.y,a1);
      a2 = fmaf(W[10],k2.z,a2);  a3 = fmaf(W[11],k2.w,a3);
      a0 = fmaf(W[12],k3.x,a0);  a1 = fmaf(W[13],k3.y,a1);
      a2 = fmaf(W[14],k3.z,a2);  a3 = fmaf(W[15],k3.w,a3);
      float dot1 = (a0+a1)+(a2+a3);
      dot1 += __shfl_xor(dot1, 32, 64);
      const float coef = bb*(vv - dot1);

      // update + z-dot interleaved
      float b0,b1,b2,b3;
      W[0] = fmaf(coef,k0.x,W[0]);  b0 = W[0]*q0.x;
      W[1] = fmaf(coef,k0.y,W[1]);  b1 = W[1]*q0.y;
      W[2] = fmaf(coef,k0.z,W[2]);  b2 = W[2]*q0.z;
      W[3] = fmaf(coef,k0.w,W[3]);  b3 = W[3]*q0.w;
      W[4] = fmaf(coef,k1.x,W[4]);  b0 = fmaf(W[4], q1.x,b0);
      W[5] = fmaf(coef,k1.y,W[5]);  b1 = fmaf(W[5], q1.y,b1);
      W[6] = fmaf(coef,k1.z,W[6]);  b2 = fmaf(W[6], q1.z,b2);
      W[7] = fmaf(coef,k1.w,W[7]);  b3 = fmaf(W[7], q1.w,b3);
      W[8] = fmaf(coef,k2.x,W[8]);  b0 = fmaf(W[8], q2.x,b0);
      W[9] = fmaf(coef,k2.y,W[9]);  b1 = fmaf(W[9], q2.y,b1);
      W[10]= fmaf(coef,k2.z,W[10]); b2 = fmaf(W[10],q2.z,b2);
      W[11]= fmaf(coef,k2.w,W[11]); b3 = fmaf(W[11],q2.w,b3);
      W[12]= fmaf(coef,k3.x,W[12]); b0 = fmaf(W[12],q3.x,b0);
      W[13]= fmaf(coef,k3.y,W[13]); b1 = fmaf(W[13],q3.y,b1);
      W[14]= fmaf(coef,k3.z,W[14]); b2 = fmaf(W[14],q3.z,b2);
      W[15]= fmaf(coef,k3.w,W[15]); b3 = fmaf(W[15],q3.w,b3);
      float z = (b0+b1)+(b2+b3);
      z += __shfl_xor(z, 32, 64);

      if (!p) (base + (size_t)s*step)[r] = z;   // overwrite dead q-slot
    }
  }
}

// ---------------- rec scan: h_t = z_t + R_t . softmax(h_{t-1}) ----------------
// One pair per 64-lane wave, same column split. The ONLY serial dependency is
// h -> exp -> LDS transpose -> dot2 -> h; the R delta-update (h-independent)
// is issued between the e-write and e-read to cover the LDS round trip.
// softmax folded: h = z + (R.e) * rcp(sum e); Ssum from the transposed
// e-registers (local adds), not a shuffle chain.
__global__ __launch_bounds__(64) void rec_scan(const float* __restrict__ qkv,
                                               float* __restrict__ hs){
  const int pair = blockIdx.x;
  const int tid  = threadIdx.x;
  const int r    = tid & 31;
  const int p    = tid >> 5;
  const int co   = p*16;

  __shared__ __align__(16) float ebuf[DH_];

  float R[16];
  #pragma unroll
  for (int i=0;i<16;i++) R[i]=0.f;
  float h = 0.f;

  const float* base = qkv + (size_t)(pair>>3)*E_ + (pair&7)*(5*DH_+2);
  const size_t step = (size_t)B_*E_;

  float4 fk[PFB_][4];
  float  fz[PFB_], fv[PFB_], fb[PFB_];
  #pragma unroll
  for (int u=0;u<PFB_;u++){
    const float* pp = base + (size_t)u*step;
    #pragma unroll
    for (int j=0;j<4;j++)
      fk[u][j] = *(const float4*)(pp + 3*DH_ + co + 4*j);    // rk
    fz[u] = pp[r];                                           // z (from ff_scan)
    fv[u] = pp[4*DH_ + r];                                   // rv[r]
    fb[u] = pp[5*DH_ + 1];                                   // rbeta
  }

  float* hp = hs + (size_t)pair*DH_ + r;

  for (int sc=0; sc<S_; sc+=PFB_){
    #pragma unroll
    for (int u=0; u<PFB_; ++u){
      const int s = sc + u;
      float4 k0=fk[u][0],k1=fk[u][1],k2=fk[u][2],k3=fk[u][3];
      const float zz=fz[u], vv=fv[u], bb=fb[u];

      // --- h-chain head: e = exp(h_prev), publish for transpose
      const float e = __expf(h);
      if (!p) ebuf[r] = e;

      if (s + PFB_ < S_){
        const float* pp = base + (size_t)(s+PFB_)*step;
        #pragma unroll
        for (int j=0;j<4;j++)
          fk[u][j] = *(const float4*)(pp + 3*DH_ + co + 4*j);
        fz[u] = pp[r];
        fv[u] = pp[4*DH_ + r];
        fb[u] = pp[5*DH_ + 1];
      }

      // --- R delta update (independent of h; covers the LDS round trip)
      float a0,a1,a2,a3;
      a0 = R[0]*k0.x;            a1 = R[1]*k0.y;
      a2 = R[2]*k0.z;            a3 = R[3]*k0.w;
      a0 = fmaf(R[4], k1.x,a0);  a1 = fmaf(R[5], k1.y,a1);
      a2 = fmaf(R[6], k1.z,a2);  a3 = fmaf(R[7], k1.w,a3);
      a0 = fmaf(R[8], k2.x,a0);  a1 = fmaf(R[9], k2.y,a1);
      a2 = fmaf(R[10],k2.z,a2);  a3 = fmaf(R[11],k2.w,a3);
      a0 = fmaf(R[12],k3.x,a0);  a1 = fmaf(R[13],k3.y,a1);
      a2 = fmaf(R[14],k3.z,a2);  a3 = fmaf(R[15],k3.w,a3);
      float dot1 = (a0+a1)+(a2+a3);
      dot1 += __shfl_xor(dot1, 32, 64);
      const float coef = bb*(vv - dot1);
      R[0] = fmaf(coef,k0.x,R[0]);  R[1] = fmaf(coef,k0.y,R[1]);
      R[2] = fmaf(coef,k0.z,R[2]);  R[3] = fmaf(coef,k0.w,R[3]);
      R[4] = fmaf(coef,k1.x,R[4]);  R[5] = fmaf(coef,k1.y,R[5]);
      R[6] = fmaf(coef,k1.z,R[6]);  R[7] = fmaf(coef,k1.w,R[7]);
      R[8] = fmaf(coef,k2.x,R[8]);  R[9] = fmaf(coef,k2.y,R[9]);
      R[10]= fmaf(coef,k2.z,R[10]); R[11]= fmaf(coef,k2.w,R[11]);
      R[12]= fmaf(coef,k3.x,R[12]); R[13]= fmaf(coef,k3.y,R[13]);
      R[14]= fmaf(coef,k3.z,R[14]); R[15]= fmaf(coef,k3.w,R[15]);

      // --- transpose read: this lane's 16 e-values
      const float4 e0 = *(const float4*)&ebuf[co+0];
      const float4 e1 = *(const float4*)&ebuf[co+4];
      const float4 e2 = *(const float4*)&ebuf[co+8];
      const float4 e3 = *(const float4*)&ebuf[co+12];

      // Ssum (local adds) in parallel with dot2 chain
      float Ss = ((e0.x+e0.y)+(e0.z+e0.w)) + ((e1.x+e1.y)+(e1.z+e1.w))
               + ((e2.x+e2.y)+(e2.z+e2.w)) + ((e3.x+e3.y)+(e3.z+e3.w));
      float d0,d1,d2,d3;
      d0 = R[0]*e0.x;            d1 = R[1]*e0.y;
      d2 = R[2]*e0.z;            d3 = R[3]*e0.w;
      d0 = fmaf(R[4], e1.x,d0);  d1 = fmaf(R[5], e1.y,d1);
      d2 = fmaf(R[6], e1.z,d2);  d3 = fmaf(R[7], e1.w,d3);
      d0 = fmaf(R[8], e2.x,d0);  d1 = fmaf(R[9], e2.y,d1);
      d2 = fmaf(R[10],e2.z,d2);  d3 = fmaf(R[11],e2.w,d3);
      d0 = fmaf(R[12],e3.x,d0);  d1 = fmaf(R[13],e3.y,d1);
      d2 = fmaf(R[14],e3.z,d2);  d3 = fmaf(R[15],e3.w,d3);
      float dot2 = (d0+d1)+(d2+d3);
      dot2 += __shfl_xor(dot2, 32, 64);
      Ss   += __shfl_xor(Ss,   32, 64);

      h = fmaf(dot2, __builtin_amdgcn_rcpf(Ss), zz);
      if (!p) hp[(size_t)s*(B_*H_*DH_)] = h;
    }
  }
}

// ---------------- launcher ----------------
extern "C" void kernel_launch(void* const* d_in, const int* in_sizes, int n_in,
                              void* d_out, int out_size, void* d_ws, size_t ws_size,
                              hipStream_t stream) {
  const float* x      = (const float*)d_in[0];
  const float* slow_W = (const float*)d_in[1];
  const float* out_W  = (const float*)d_in[2];
  const float* ln_g   = (const float*)d_in[3];
  const float* ln_b   = (const float*)d_in[4];
  float* out = (float*)d_out;

  float* o   = out;                          // LN out lives in d_out (overwritten later)
  float* qkv = (float*)d_ws;                 // [SB][E]
  float* hs  = qkv + (size_t)SB_*E_;         // [SB][D]

  ln_kernel<<<SB_, 256, 0, stream>>>(x, ln_g, ln_b, o);

  dim3 g1((E_ + 127)/128, SB_/128);
  gemm_bt<false><<<g1, 256, 0, stream>>>(o, slow_W, nullptr, qkv, SB_, E_, D_);

  act_kernel<<<SB_, 256, 0, stream>>>(qkv);

  ff_scan<<<B_*H_, 64, 0, stream>>>(qkv);
  rec_scan<<<B_*H_, 64, 0, stream>>>(qkv, hs);

  dim3 g2(D_/128, SB_/128);
  gemm_bt<true><<<g2, 256, 0, stream>>>(hs, out_W, x, out, SB_, D_, D_);
}

// Round 4
// 789.212 us; speedup vs baseline: 1.0892x; 1.0892x over previous
//
#include <hip/hip_runtime.h>
#include <hip/hip_bf16.h>
#include <math.h>

// Problem constants (from reference)
#define S_   512
#define B_   32
#define D_   256
#define H_   8
#define DH_  32
#define E_   (H_*(5*DH_+2))   // 1296
#define SB_  (S_*B_)          // 16384
#define LN_EPSF 1e-5f

// ---------------- reductions ----------------
__device__ __forceinline__ float wave_sum64(float v){
  #pragma unroll
  for (int m = 32; m >= 1; m >>= 1) v += __shfl_xor(v, m, 64);
  return v;
}
__device__ __forceinline__ float gsum32(float v){
  #pragma unroll
  for (int m = 16; m >= 1; m >>= 1) v += __shfl_xor(v, m, 32);
  return v;
}
__device__ __forceinline__ float gmax32(float v){
  #pragma unroll
  for (int m = 16; m >= 1; m >>= 1) v = fmaxf(v, __shfl_xor(v, m, 32));
  return v;
}

// ---------------- LayerNorm: one block per (s,b) row ----------------
__global__ __launch_bounds__(256) void ln_kernel(const float* __restrict__ x,
                                                 const float* __restrict__ g,
                                                 const float* __restrict__ b,
                                                 float* __restrict__ o){
  __shared__ float sbuf[4];
  const int row = blockIdx.x, tid = threadIdx.x;
  const float v = x[(size_t)row*D_ + tid];
  float s = wave_sum64(v);
  if ((tid & 63) == 0) sbuf[tid >> 6] = s;
  __syncthreads();
  const float mu = (sbuf[0]+sbuf[1]+sbuf[2]+sbuf[3]) * (1.f/D_);
  __syncthreads();
  const float d = v - mu;
  float s2 = wave_sum64(d*d);
  if ((tid & 63) == 0) sbuf[tid >> 6] = s2;
  __syncthreads();
  const float var = (sbuf[0]+sbuf[1]+sbuf[2]+sbuf[3]) * (1.f/D_);
  const float rstd = rsqrtf(var + LN_EPSF);
  o[(size_t)row*D_ + tid] = d*rstd*g[tid] + b[tid];
}

// ---------------- GEMM (C[m][n] = sum_k A[m][k]*B[n][k] (+ X)) ----------------
template<bool ADD>
__global__ __launch_bounds__(256) void gemm_bt(const float* __restrict__ A,
                                               const float* __restrict__ Bm,
                                               const float* __restrict__ X,
                                               float* __restrict__ C,
                                               int M, int N, int K){
  const int BM=128, BN=128, BK=16;
  __shared__ float As[BK][BM+4];
  __shared__ float Bs[BK][BN+4];
  const int tid = threadIdx.x;
  const int m0 = blockIdx.y*BM, n0 = blockIdx.x*BN;
  const int tx = tid & 15, ty = tid >> 4;
  float acc[8][8];
  #pragma unroll
  for (int i=0;i<8;i++)
    #pragma unroll
    for (int j=0;j<8;j++) acc[i][j]=0.f;

  const int lrow = tid >> 2;         // 0..63
  const int lcol = (tid & 3) << 2;   // 0,4,8,12

  for (int k0=0;k0<K;k0+=BK){
    #pragma unroll
    for (int p=0;p<2;p++){
      const int row = lrow + p*64;
      const float4 va = *(const float4*)(A + (size_t)(m0+row)*K + k0 + lcol);
      As[lcol+0][row]=va.x; As[lcol+1][row]=va.y; As[lcol+2][row]=va.z; As[lcol+3][row]=va.w;
      const int nrow = n0 + row;
      float4 vb = make_float4(0.f,0.f,0.f,0.f);
      if (nrow < N) vb = *(const float4*)(Bm + (size_t)nrow*K + k0 + lcol);
      Bs[lcol+0][row]=vb.x; Bs[lcol+1][row]=vb.y; Bs[lcol+2][row]=vb.z; Bs[lcol+3][row]=vb.w;
    }
    __syncthreads();
    #pragma unroll
    for (int k=0;k<BK;k++){
      float a[8], bb[8];
      *(float4*)&a[0]  = *(const float4*)&As[k][ty*8];
      *(float4*)&a[4]  = *(const float4*)&As[k][ty*8+4];
      *(float4*)&bb[0] = *(const float4*)&Bs[k][tx*8];
      *(float4*)&bb[4] = *(const float4*)&Bs[k][tx*8+4];
      #pragma unroll
      for (int i=0;i<8;i++)
        #pragma unroll
        for (int j=0;j<8;j++) acc[i][j] = fmaf(a[i], bb[j], acc[i][j]);
    }
    __syncthreads();
  }
  #pragma unroll
  for (int i=0;i<8;i++){
    const size_t m = (size_t)(m0 + ty*8 + i);
    #pragma unroll
    for (int j=0;j<8;j+=4){
      const int n = n0 + tx*8 + j;
      if (n < N){
        float4 r = make_float4(acc[i][j],acc[i][j+1],acc[i][j+2],acc[i][j+3]);
        if (ADD){
          const float4 xv = *(const float4*)(X + m*N + n);
          r.x+=xv.x; r.y+=xv.y; r.z+=xv.z; r.w+=xv.w;
        }
        *(float4*)(C + m*N + n) = r;
      }
    }
  }
}

// ---------------- activations, in-place on qkv [SB][H][162] ----------------
__global__ __launch_bounds__(256) void act_kernel(float* __restrict__ qkv){
  const int sb = blockIdx.x;
  const int head = threadIdx.x >> 5;
  const int i = threadIdx.x & 31;
  float* base = qkv + (size_t)sb*E_ + head*(5*DH_+2);
  float qv  = base[i];
  float kv  = base[DH_ + i];
  float rkv = base[3*DH_ + i];
  qv = qv > 0.f ? qv + 1.f : __expf(qv);
  kv = kv > 0.f ? kv + 1.f : __expf(kv);
  const float qs = gsum32(qv);
  const float ks = gsum32(kv);
  const float rm = gmax32(rkv);
  const float re = __expf(rkv - rm);
  const float rs = gsum32(re);
  base[i]         = qv / qs;
  base[DH_ + i]   = kv / ks;
  base[3*DH_ + i] = re / rs;
  if (i < 2){
    const float bv = base[5*DH_ + i];
    base[5*DH_ + i] = 1.f/(1.f + __expf(-bv));
  }
}

// ---------------- ff scan: z_t = W_t . q_t, delta-rule W ----------------
// 2 pairs per wave (one per 32-lane half); lane r owns the FULL row r of W
// (32 regs). k,q broadcast-loaded (same addr within a half -> 1 fetch).
// ZERO cross-lane ops: dot1/z are lane-local 32-elem dots. PF=2 register
// prefetch; launch_bounds(64,1) so the prefetch state stays in VGPRs.
// z overwrites qkv's dead q-slot.
__global__ __launch_bounds__(64,1) void ff_scan(float* __restrict__ qkv){
  const int tid  = threadIdx.x;
  const int half = tid >> 5;
  const int r    = tid & 31;
  const int pair = blockIdx.x*2 + half;     // b*H + h  (same b for both halves)
  float* base = qkv + (size_t)(pair>>3)*E_ + (pair&7)*(5*DH_+2);
  const size_t step = (size_t)B_*E_;

  float W[DH_];
  #pragma unroll
  for (int i=0;i<DH_;i++) W[i]=0.f;

  float4 fq[2][8], fk[2][8];
  float  fv[2], fb[2];
  #pragma unroll
  for (int u=0;u<2;u++){
    const float* pp = base + (size_t)u*step;
    #pragma unroll
    for (int j=0;j<8;j++){
      fq[u][j] = *(const float4*)(pp + 4*j);            // q[0..31]
      fk[u][j] = *(const float4*)(pp + DH_ + 4*j);      // k[0..31]
    }
    fv[u] = pp[2*DH_ + r];                              // v[r]
    fb[u] = pp[5*DH_];                                  // beta
  }

  for (int sc=0; sc<S_; sc+=2){
    #pragma unroll
    for (int u=0; u<2; ++u){
      const int s = sc + u;
      float q[DH_], k[DH_];
      #pragma unroll
      for (int j=0;j<8;j++){
        *(float4*)&q[4*j] = fq[u][j];
        *(float4*)&k[4*j] = fk[u][j];
      }
      const float vv = fv[u], bb = fb[u];
      if (s + 2 < S_){                                  // uniform branch
        const float* pp = base + (size_t)(s+2)*step;
        #pragma unroll
        for (int j=0;j<8;j++){
          fq[u][j] = *(const float4*)(pp + 4*j);
          fk[u][j] = *(const float4*)(pp + DH_ + 4*j);
        }
        fv[u] = pp[2*DH_ + r];
        fb[u] = pp[5*DH_];
      }

      // dot1 = W[r,:] . k  (local, 4-way split)
      float a0=0.f,a1=0.f,a2=0.f,a3=0.f;
      #pragma unroll
      for (int c=0;c<DH_;c+=4){
        a0=fmaf(W[c+0],k[c+0],a0); a1=fmaf(W[c+1],k[c+1],a1);
        a2=fmaf(W[c+2],k[c+2],a2); a3=fmaf(W[c+3],k[c+3],a3);
      }
      const float coef = bb*(vv - ((a0+a1)+(a2+a3)));

      // W[r,:] += coef*k ; z_r = W_new[r,:] . q  (interleaved)
      float b0=0.f,b1=0.f,b2=0.f,b3=0.f;
      #pragma unroll
      for (int c=0;c<DH_;c+=4){
        W[c+0]=fmaf(coef,k[c+0],W[c+0]); b0=fmaf(W[c+0],q[c+0],b0);
        W[c+1]=fmaf(coef,k[c+1],W[c+1]); b1=fmaf(W[c+1],q[c+1],b1);
        W[c+2]=fmaf(coef,k[c+2],W[c+2]); b2=fmaf(W[c+2],q[c+2],b2);
        W[c+3]=fmaf(coef,k[c+3],W[c+3]); b3=fmaf(W[c+3],q[c+3],b3);
      }
      (base + (size_t)s*step)[r] = (b0+b1)+(b2+b3);     // z -> dead q-slot
    }
  }
}

// ---------------- rec scan: h_t = z_t + R_t . softmax(h_{t-1}) ----------------
// 2 pairs per wave, lane r owns full row r of R. The only cross-lane op is
// the h->e broadcast: 1 LDS write + 8 same-address ds_read_b128 (2-way
// conflict = free). R's delta update (h-independent, 96 fma) sits between the
// e-write and e-read to cover the LDS round trip. softmax folded:
// h = z + (R.e) * rcp(sum e); Ssum is a local 31-add tree after the read.
__global__ __launch_bounds__(64,1) void rec_scan(const float* __restrict__ qkv,
                                                 float* __restrict__ hs){
  const int tid  = threadIdx.x;
  const int half = tid >> 5;
  const int r    = tid & 31;
  const int pair = blockIdx.x*2 + half;
  const float* base = qkv + (size_t)(pair>>3)*E_ + (pair&7)*(5*DH_+2);
  const size_t step = (size_t)B_*E_;

  __shared__ __align__(16) float ebuf[2][DH_];

  float R[DH_];
  #pragma unroll
  for (int i=0;i<DH_;i++) R[i]=0.f;
  float h = 0.f;

  float4 fk[2][8];
  float  fz[2], fv[2], fb[2];
  #pragma unroll
  for (int u=0;u<2;u++){
    const float* pp = base + (size_t)u*step;
    #pragma unroll
    for (int j=0;j<8;j++)
      fk[u][j] = *(const float4*)(pp + 3*DH_ + 4*j);    // rk[0..31]
    fz[u] = pp[r];                                      // z (from ff_scan)
    fv[u] = pp[4*DH_ + r];                              // rv[r]
    fb[u] = pp[5*DH_ + 1];                              // rbeta
  }

  float* hp = hs + (size_t)pair*DH_ + r;

  for (int sc=0; sc<S_; sc+=2){
    #pragma unroll
    for (int u=0; u<2; ++u){
      const int s = sc + u;

      // ---- h-chain head: publish e = exp(h_prev)
      const float e = __expf(h);
      ebuf[half][r] = e;

      float k[DH_];
      #pragma unroll
      for (int j=0;j<8;j++) *(float4*)&k[4*j] = fk[u][j];
      const float zz=fz[u], vv=fv[u], bb=fb[u];
      if (s + 2 < S_){
        const float* pp = base + (size_t)(s+2)*step;
        #pragma unroll
        for (int j=0;j<8;j++)
          fk[u][j] = *(const float4*)(pp + 3*DH_ + 4*j);
        fz[u] = pp[r];
        fv[u] = pp[4*DH_ + r];
        fb[u] = pp[5*DH_ + 1];
      }

      // ---- R delta update (h-independent; covers the LDS round trip)
      float a0=0.f,a1=0.f,a2=0.f,a3=0.f;
      #pragma unroll
      for (int c=0;c<DH_;c+=4){
        a0=fmaf(R[c+0],k[c+0],a0); a1=fmaf(R[c+1],k[c+1],a1);
        a2=fmaf(R[c+2],k[c+2],a2); a3=fmaf(R[c+3],k[c+3],a3);
      }
      const float coef = bb*(vv - ((a0+a1)+(a2+a3)));
      #pragma unroll
      for (int c=0;c<DH_;c+=4){
        R[c+0]=fmaf(coef,k[c+0],R[c+0]); R[c+1]=fmaf(coef,k[c+1],R[c+1]);
        R[c+2]=fmaf(coef,k[c+2],R[c+2]); R[c+3]=fmaf(coef,k[c+3],R[c+3]);
      }

      // ---- read the full e-vector of OUR half (broadcast reads)
      float ev[DH_];
      #pragma unroll
      for (int j=0;j<8;j++)
        *(float4*)&ev[4*j] = *(const float4*)&ebuf[half][4*j];

      // Ssum: local add tree (depth 5), overlaps the dot2 chain
      float t0=(ev[0]+ev[1])+(ev[2]+ev[3]),   t1=(ev[4]+ev[5])+(ev[6]+ev[7]);
      float t2=(ev[8]+ev[9])+(ev[10]+ev[11]), t3=(ev[12]+ev[13])+(ev[14]+ev[15]);
      float t4=(ev[16]+ev[17])+(ev[18]+ev[19]),t5=(ev[20]+ev[21])+(ev[22]+ev[23]);
      float t6=(ev[24]+ev[25])+(ev[26]+ev[27]),t7=(ev[28]+ev[29])+(ev[30]+ev[31]);
      const float Ss = ((t0+t1)+(t2+t3)) + ((t4+t5)+(t6+t7));

      // dot2 = R_new[r,:] . e  (local)
      float d0=0.f,d1=0.f,d2=0.f,d3=0.f;
      #pragma unroll
      for (int c=0;c<DH_;c+=4){
        d0=fmaf(R[c+0],ev[c+0],d0); d1=fmaf(R[c+1],ev[c+1],d1);
        d2=fmaf(R[c+2],ev[c+2],d2); d3=fmaf(R[c+3],ev[c+3],d3);
      }
      const float dot2 = (d0+d1)+(d2+d3);

      h = fmaf(dot2, __builtin_amdgcn_rcpf(Ss), zz);
      hp[(size_t)s*(B_*H_*DH_)] = h;
    }
  }
}

// ---------------- launcher ----------------
extern "C" void kernel_launch(void* const* d_in, const int* in_sizes, int n_in,
                              void* d_out, int out_size, void* d_ws, size_t ws_size,
                              hipStream_t stream) {
  const float* x      = (const float*)d_in[0];
  const float* slow_W = (const float*)d_in[1];
  const float* out_W  = (const float*)d_in[2];
  const float* ln_g   = (const float*)d_in[3];
  const float* ln_b   = (const float*)d_in[4];
  float* out = (float*)d_out;

  float* o   = out;                          // LN out lives in d_out (overwritten later)
  float* qkv = (float*)d_ws;                 // [SB][E]
  float* hs  = qkv + (size_t)SB_*E_;         // [SB][D]

  ln_kernel<<<SB_, 256, 0, stream>>>(x, ln_g, ln_b, o);

  dim3 g1((E_ + 127)/128, SB_/128);
  gemm_bt<false><<<g1, 256, 0, stream>>>(o, slow_W, nullptr, qkv, SB_, E_, D_);

  act_kernel<<<SB_, 256, 0, stream>>>(qkv);

  ff_scan<<<B_*H_/2, 64, 0, stream>>>(qkv);
  rec_scan<<<B_*H_/2, 64, 0, stream>>>(qkv, hs);

  dim3 g2(D_/128, SB_/128);
  gemm_bt<true><<<g2, 256, 0, stream>>>(hs, out_W, x, out, SB_, D_, D_);
}

// Round 5
// 563.871 us; speedup vs baseline: 1.5245x; 1.3996x over previous
//
#include <hip/hip_runtime.h>
#include <hip/hip_bf16.h>
#include <math.h>

// Problem constants (from reference)
#define S_   512
#define B_   32
#define D_   256
#define H_   8
#define DH_  32
#define E_   (H_*(5*DH_+2))   // 1296
#define SB_  (S_*B_)          // 16384
#define LN_EPSF 1e-5f

#define CH_   64              // scan chunk (steps)
#define NCH_  (S_/CH_)        // 8
#define ROWF_ 162             // floats per (pair,s) row in qkvT
#define CHF_  (CH_*ROWF_)     // 10368 floats per chunk
#define CHF4_ (CHF_/4)        // 2592 float4 per chunk

// ---------------- reductions ----------------
__device__ __forceinline__ float wave_sum64(float v){
  #pragma unroll
  for (int m = 32; m >= 1; m >>= 1) v += __shfl_xor(v, m, 64);
  return v;
}
__device__ __forceinline__ float gsum32(float v){
  #pragma unroll
  for (int m = 16; m >= 1; m >>= 1) v += __shfl_xor(v, m, 32);
  return v;
}
__device__ __forceinline__ float gmax32(float v){
  #pragma unroll
  for (int m = 16; m >= 1; m >>= 1) v = fmaxf(v, __shfl_xor(v, m, 32));
  return v;
}

// ---------------- LayerNorm: one block per (s,b) row ----------------
__global__ __launch_bounds__(256) void ln_kernel(const float* __restrict__ x,
                                                 const float* __restrict__ g,
                                                 const float* __restrict__ b,
                                                 float* __restrict__ o){
  __shared__ float sbuf[4];
  const int row = blockIdx.x, tid = threadIdx.x;
  const float v = x[(size_t)row*D_ + tid];
  float s = wave_sum64(v);
  if ((tid & 63) == 0) sbuf[tid >> 6] = s;
  __syncthreads();
  const float mu = (sbuf[0]+sbuf[1]+sbuf[2]+sbuf[3]) * (1.f/D_);
  __syncthreads();
  const float d = v - mu;
  float s2 = wave_sum64(d*d);
  if ((tid & 63) == 0) sbuf[tid >> 6] = s2;
  __syncthreads();
  const float var = (sbuf[0]+sbuf[1]+sbuf[2]+sbuf[3]) * (1.f/D_);
  const float rstd = rsqrtf(var + LN_EPSF);
  o[(size_t)row*D_ + tid] = d*rstd*g[tid] + b[tid];
}

// ------- GEMM1: qkvT[((b*8+head)*512 + s)*162 + jj] = sum_k o[m][k] W[n][k] -------
// f32 vector tile 128x128x16; epilogue scatters to the transposed layout
// (per store instr: runs of ~512B contiguous per ty-group -> acceptable).
__global__ __launch_bounds__(256) void gemm_qkvT(const float* __restrict__ A,
                                                 const float* __restrict__ Bm,
                                                 float* __restrict__ qkvT,
                                                 int M, int N, int K){
  const int BM=128, BN=128, BK=16;
  __shared__ float As[BK][BM+4];
  __shared__ float Bs[BK][BN+4];
  const int tid = threadIdx.x;
  const int m0 = blockIdx.y*BM, n0 = blockIdx.x*BN;
  const int tx = tid & 15, ty = tid >> 4;
  float acc[8][8];
  #pragma unroll
  for (int i=0;i<8;i++)
    #pragma unroll
    for (int j=0;j<8;j++) acc[i][j]=0.f;

  const int lrow = tid >> 2;
  const int lcol = (tid & 3) << 2;

  for (int k0=0;k0<K;k0+=BK){
    #pragma unroll
    for (int p=0;p<2;p++){
      const int row = lrow + p*64;
      const float4 va = *(const float4*)(A + (size_t)(m0+row)*K + k0 + lcol);
      As[lcol+0][row]=va.x; As[lcol+1][row]=va.y; As[lcol+2][row]=va.z; As[lcol+3][row]=va.w;
      const int nrow = n0 + row;
      float4 vb = make_float4(0.f,0.f,0.f,0.f);
      if (nrow < N) vb = *(const float4*)(Bm + (size_t)nrow*K + k0 + lcol);
      Bs[lcol+0][row]=vb.x; Bs[lcol+1][row]=vb.y; Bs[lcol+2][row]=vb.z; Bs[lcol+3][row]=vb.w;
    }
    __syncthreads();
    #pragma unroll
    for (int k=0;k<BK;k++){
      float a[8], bb[8];
      *(float4*)&a[0]  = *(const float4*)&As[k][ty*8];
      *(float4*)&a[4]  = *(const float4*)&As[k][ty*8+4];
      *(float4*)&bb[0] = *(const float4*)&Bs[k][tx*8];
      *(float4*)&bb[4] = *(const float4*)&Bs[k][tx*8+4];
      #pragma unroll
      for (int i=0;i<8;i++)
        #pragma unroll
        for (int j=0;j<8;j++) acc[i][j] = fmaf(a[i], bb[j], acc[i][j]);
    }
    __syncthreads();
  }
  #pragma unroll
  for (int i=0;i<8;i++){
    const int m = m0 + ty*8 + i;
    const int s = m >> 5, bq = m & 31;
    #pragma unroll
    for (int j=0;j<8;j++){
      const int n = n0 + tx*8 + j;
      if (n < N){
        const unsigned head = (unsigned)n / 162u;
        const unsigned jj   = (unsigned)n - head*162u;
        qkvT[((size_t)(bq*8u+head)*S_ + s)*ROWF_ + jj] = acc[i][j];
      }
    }
  }
}

// ---------------- activations, in-place on qkvT rows [162] ----------------
// row chunk: q(0:32) k(32:64) v(64:96) rk(96:128) rv(128:160) beta(160) rbeta(161)
__global__ __launch_bounds__(256) void act2_kernel(float* __restrict__ qkvT){
  const int row = blockIdx.x*8 + (threadIdx.x >> 5);
  const int i = threadIdx.x & 31;
  float* base = qkvT + (size_t)row*ROWF_;
  float qv  = base[i];
  float kv  = base[DH_ + i];
  float rkv = base[3*DH_ + i];
  qv = qv > 0.f ? qv + 1.f : __expf(qv);   // elu+1
  kv = kv > 0.f ? kv + 1.f : __expf(kv);
  const float qs = gsum32(qv);
  const float ks = gsum32(kv);
  const float rm = gmax32(rkv);
  const float re = __expf(rkv - rm);
  const float rs = gsum32(re);
  base[i]         = qv / qs;
  base[DH_ + i]   = kv / ks;
  base[3*DH_ + i] = re / rs;
  if (i < 2){
    const float bv = base[5*DH_ + i];
    base[5*DH_ + i] = 1.f/(1.f + __expf(-bv));
  }
}

// ---------------- fused scan: wave-specialized producer/consumer ----------------
// 256 blocks (1 per (b,h) pair) x 128 threads (2 waves), 1 block/CU (141KB LDS).
// wave0 (ff): chunk i -> z into zbuf; then reg-stages chunk i+1 into stg[(i+1)%3].
// wave1 (rec): chunk i-1 (one behind), consuming zbuf. Barrier per chunk.
// All per-step inputs come from LDS (bulk-staged) -> no per-step global latency.
__global__ __launch_bounds__(128,1) void scan_fused(const float* __restrict__ qkvT,
                                                    float* __restrict__ hs){
  const int pair = blockIdx.x;
  const int tid  = threadIdx.x;
  const int wid  = tid >> 6;          // 0 = ff wave, 1 = rec wave
  const int lane = tid & 63;
  const int r    = lane & 31;
  const int p    = lane >> 5;         // ff column half

  __shared__ float stg[3][CHF_];      // 3 x 41.5KB rotating chunk buffers
  __shared__ float zbuf[2][CH_][DH_]; // ff -> rec, per-chunk parity
  __shared__ float ebuf[2][DH_];      // rec e-broadcast, per-step parity

  const float* gbase = qkvT + (size_t)pair*S_*ROWF_;
  const int b  = pair >> 3;
  const int hh = pair & 7;

  // persistent state (per wave; the other wave's regs are dead weight)
  float W[16];                        // ff: row r, cols p*16..p*16+15
  #pragma unroll
  for (int i=0;i<16;i++) W[i]=0.f;
  float R[DH_];                       // rec: full row r (duplicated halves)
  #pragma unroll
  for (int i=0;i<DH_;i++) R[i]=0.f;
  float h = 0.f;

  // prologue: both waves stage chunk 0
  {
    const float4* gs = (const float4*)gbase;
    float4* ls = (float4*)stg[0];
    for (int t = tid; t < CHF4_; t += 128) ls[t] = gs[t];
  }
  __syncthreads();

  int m0=0, m1=1, m2=2;   // m0 = i%3 (ff compute), m1=(i+1)%3 (ff stage), m2=(i+2)%3=(i-1)%3 (rec)
  for (int i = 0; i <= NCH_; ++i){
    if (wid == 0){
      if (i < NCH_){
        // ---------- ff: chunk i from stg[m0] ----------
        const float* sb = stg[m0];
        #pragma unroll 2
        for (int t = 0; t < CH_; ++t){
          const float* row = sb + t*ROWF_;
          float q[16], k[16];
          #pragma unroll
          for (int j=0;j<4;j++){
            *(float4*)&q[4*j] = *(const float4*)(row + p*16 + 4*j);
            *(float4*)&k[4*j] = *(const float4*)(row + DH_ + p*16 + 4*j);
          }
          const float vv = row[2*DH_ + r];
          const float bb = row[5*DH_];

          float a0=0.f,a1=0.f,a2=0.f,a3=0.f;
          #pragma unroll
          for (int c=0;c<16;c+=4){
            a0=fmaf(W[c+0],k[c+0],a0); a1=fmaf(W[c+1],k[c+1],a1);
            a2=fmaf(W[c+2],k[c+2],a2); a3=fmaf(W[c+3],k[c+3],a3);
          }
          float dot1 = (a0+a1)+(a2+a3);
          dot1 += __shfl_xor(dot1, 32, 64);
          const float coef = bb*(vv - dot1);

          float b0=0.f,b1=0.f,b2=0.f,b3=0.f;
          #pragma unroll
          for (int c=0;c<16;c+=4){
            W[c+0]=fmaf(coef,k[c+0],W[c+0]); b0=fmaf(W[c+0],q[c+0],b0);
            W[c+1]=fmaf(coef,k[c+1],W[c+1]); b1=fmaf(W[c+1],q[c+1],b1);
            W[c+2]=fmaf(coef,k[c+2],W[c+2]); b2=fmaf(W[c+2],q[c+2],b2);
            W[c+3]=fmaf(coef,k[c+3],W[c+3]); b3=fmaf(W[c+3],q[c+3],b3);
          }
          float z = (b0+b1)+(b2+b3);
          z += __shfl_xor(z, 32, 64);
          if (lane < DH_) zbuf[i&1][t][r] = z;
        }
        // ---------- stage chunk i+1 into stg[m1] (64 lanes, batched) ----------
        if (i+1 < NCH_){
          const float4* gs = (const float4*)(gbase + (size_t)(i+1)*CHF_);
          float4* ls = (float4*)stg[m1];
          float4 tmp[8];
          for (int t0 = 0; t0 < 2560; t0 += 512){
            #pragma unroll
            for (int j=0;j<8;j++) tmp[j] = gs[t0 + j*64 + lane];
            #pragma unroll
            for (int j=0;j<8;j++) ls[t0 + j*64 + lane] = tmp[j];
          }
          if (lane < 32) ls[2560 + lane] = gs[2560 + lane];
        }
      }
    } else {
      if (i >= 1){
        // ---------- rec: chunk i-1 from stg[m2] + zbuf ----------
        const float* sb = stg[m2];
        const int par = (i-1)&1;
        const int s0  = (i-1)*CH_;
        #pragma unroll 2
        for (int t = 0; t < CH_; ++t){
          const float* row = sb + t*ROWF_;
          // h-chain head
          const float e = __expf(h);
          ebuf[t&1][r] = e;                 // halves write same value: benign

          float k[DH_];
          #pragma unroll
          for (int j=0;j<8;j++)
            *(float4*)&k[4*j] = *(const float4*)(row + 3*DH_ + 4*j);
          const float vv = row[4*DH_ + r];
          const float bb = row[5*DH_ + 1];
          const float zz = zbuf[par][t][r];

          // R delta update (h-independent; fills the ebuf round trip)
          float a0=0.f,a1=0.f,a2=0.f,a3=0.f;
          #pragma unroll
          for (int c=0;c<DH_;c+=4){
            a0=fmaf(R[c+0],k[c+0],a0); a1=fmaf(R[c+1],k[c+1],a1);
            a2=fmaf(R[c+2],k[c+2],a2); a3=fmaf(R[c+3],k[c+3],a3);
          }
          const float coef = bb*(vv - ((a0+a1)+(a2+a3)));
          #pragma unroll
          for (int c=0;c<DH_;c+=4){
            R[c+0]=fmaf(coef,k[c+0],R[c+0]); R[c+1]=fmaf(coef,k[c+1],R[c+1]);
            R[c+2]=fmaf(coef,k[c+2],R[c+2]); R[c+3]=fmaf(coef,k[c+3],R[c+3]);
          }

          // read full e vector (broadcast b128)
          float ev[DH_];
          #pragma unroll
          for (int j=0;j<8;j++)
            *(float4*)&ev[4*j] = *(const float4*)&ebuf[t&1][4*j];

          // Ssum local tree (off-chain) + dot2
          float t0_=(ev[0]+ev[1])+(ev[2]+ev[3]),   t1_=(ev[4]+ev[5])+(ev[6]+ev[7]);
          float t2_=(ev[8]+ev[9])+(ev[10]+ev[11]), t3_=(ev[12]+ev[13])+(ev[14]+ev[15]);
          float t4_=(ev[16]+ev[17])+(ev[18]+ev[19]),t5_=(ev[20]+ev[21])+(ev[22]+ev[23]);
          float t6_=(ev[24]+ev[25])+(ev[26]+ev[27]),t7_=(ev[28]+ev[29])+(ev[30]+ev[31]);
          const float Ss = ((t0_+t1_)+(t2_+t3_)) + ((t4_+t5_)+(t6_+t7_));

          float d0=0.f,d1=0.f,d2=0.f,d3=0.f;
          #pragma unroll
          for (int c=0;c<DH_;c+=4){
            d0=fmaf(R[c+0],ev[c+0],d0); d1=fmaf(R[c+1],ev[c+1],d1);
            d2=fmaf(R[c+2],ev[c+2],d2); d3=fmaf(R[c+3],ev[c+3],d3);
          }
          const float dot2 = (d0+d1)+(d2+d3);

          h = fmaf(dot2, __builtin_amdgcn_rcpf(Ss), zz);
          if (lane < DH_)
            hs[((size_t)(s0+t)*B_ + b)*D_ + hh*DH_ + r] = h;
        }
      }
    }
    __syncthreads();
    const int tswp = m0; m0 = m1; m1 = m2; m2 = tswp;
  }
}

// ---------------- GEMM2 (C = hs . out_W^T + x) ----------------
__global__ __launch_bounds__(256) void gemm_out(const float* __restrict__ A,
                                                const float* __restrict__ Bm,
                                                const float* __restrict__ X,
                                                float* __restrict__ C,
                                                int M, int N, int K){
  const int BM=128, BN=128, BK=16;
  __shared__ float As[BK][BM+4];
  __shared__ float Bs[BK][BN+4];
  const int tid = threadIdx.x;
  const int m0 = blockIdx.y*BM, n0 = blockIdx.x*BN;
  const int tx = tid & 15, ty = tid >> 4;
  float acc[8][8];
  #pragma unroll
  for (int i=0;i<8;i++)
    #pragma unroll
    for (int j=0;j<8;j++) acc[i][j]=0.f;

  const int lrow = tid >> 2;
  const int lcol = (tid & 3) << 2;

  for (int k0=0;k0<K;k0+=BK){
    #pragma unroll
    for (int p=0;p<2;p++){
      const int row = lrow + p*64;
      const float4 va = *(const float4*)(A + (size_t)(m0+row)*K + k0 + lcol);
      As[lcol+0][row]=va.x; As[lcol+1][row]=va.y; As[lcol+2][row]=va.z; As[lcol+3][row]=va.w;
      const float4 vb = *(const float4*)(Bm + (size_t)(n0+row)*K + k0 + lcol);
      Bs[lcol+0][row]=vb.x; Bs[lcol+1][row]=vb.y; Bs[lcol+2][row]=vb.z; Bs[lcol+3][row]=vb.w;
    }
    __syncthreads();
    #pragma unroll
    for (int k=0;k<BK;k++){
      float a[8], bb[8];
      *(float4*)&a[0]  = *(const float4*)&As[k][ty*8];
      *(float4*)&a[4]  = *(const float4*)&As[k][ty*8+4];
      *(float4*)&bb[0] = *(const float4*)&Bs[k][tx*8];
      *(float4*)&bb[4] = *(const float4*)&Bs[k][tx*8+4];
      #pragma unroll
      for (int i=0;i<8;i++)
        #pragma unroll
        for (int j=0;j<8;j++) acc[i][j] = fmaf(a[i], bb[j], acc[i][j]);
    }
    __syncthreads();
  }
  #pragma unroll
  for (int i=0;i<8;i++){
    const size_t m = (size_t)(m0 + ty*8 + i);
    #pragma unroll
    for (int j=0;j<8;j+=4){
      const int n = n0 + tx*8 + j;
      float4 rr = make_float4(acc[i][j],acc[i][j+1],acc[i][j+2],acc[i][j+3]);
      const float4 xv = *(const float4*)(X + m*N + n);
      rr.x+=xv.x; rr.y+=xv.y; rr.z+=xv.z; rr.w+=xv.w;
      *(float4*)(C + m*N + n) = rr;
    }
  }
}

// ---------------- launcher ----------------
extern "C" void kernel_launch(void* const* d_in, const int* in_sizes, int n_in,
                              void* d_out, int out_size, void* d_ws, size_t ws_size,
                              hipStream_t stream) {
  const float* x      = (const float*)d_in[0];
  const float* slow_W = (const float*)d_in[1];
  const float* out_W  = (const float*)d_in[2];
  const float* ln_g   = (const float*)d_in[3];
  const float* ln_b   = (const float*)d_in[4];
  float* out = (float*)d_out;

  float* o    = out;                          // LN out in d_out (overwritten by GEMM2)
  float* qkvT = (float*)d_ws;                 // [256 pairs][512 s][162]  (84.9MB)
  float* hs   = qkvT + (size_t)B_*H_*S_*ROWF_;// [SB][D] (16.8MB)

  ln_kernel<<<SB_, 256, 0, stream>>>(x, ln_g, ln_b, o);

  dim3 g1((E_ + 127)/128, SB_/128);           // (11, 128)
  gemm_qkvT<<<g1, 256, 0, stream>>>(o, slow_W, qkvT, SB_, E_, D_);

  act2_kernel<<<B_*H_*S_/8, 256, 0, stream>>>(qkvT);

  scan_fused<<<B_*H_, 128, 0, stream>>>(qkvT, hs);

  dim3 g2(D_/128, SB_/128);                   // (2, 128)
  gemm_out<<<g2, 256, 0, stream>>>(hs, out_W, x, out, SB_, D_, D_);
}